// Round 6
// baseline (847.090 us; speedup 1.0000x reference)
//
#include <hip/hip_runtime.h>
#include <hip/hip_cooperative_groups.h>
#include <math.h>

namespace cg = cooperative_groups;

#define WWIN 9
#define BATCH 256
#define FEAT 51
#define TT 459          // WWIN*FEAT
#define EMBD 6
#define HID 306
#define G3 918
#define FFND 12
#define TOPM 80
#define MAXTASK 320

__device__ __forceinline__ float leakyf(float v){ return v >= 0.f ? v : 0.01f*v; }
__device__ __forceinline__ float sigmf(float v){ return 1.f/(1.f+__expf(-v)); }

__device__ __forceinline__ unsigned fkey(float s){
    unsigned fb = __float_as_uint(s);
    unsigned m = (unsigned)((int)fb >> 31);
    return fb ^ (m | 0x80000000u);
}
__device__ __forceinline__ float fkey_inv(unsigned k){
    unsigned fb = (k & 0x80000000u) ? (k ^ 0x80000000u) : ~k;
    return __uint_as_float(fb);
}

// ---- DPP wave64 reductions (rocPRIM pattern); ctrl/mask must be constexpr ----
template<int CTRL, int RMASK>
__device__ __forceinline__ float dpp_add(float v){
    int r = __builtin_amdgcn_update_dpp(0, __float_as_int(v), CTRL, RMASK, 0xf, true);
    return v + __int_as_float(r);
}
__device__ __forceinline__ float wave_fsum(float v){
    v = dpp_add<0x111, 0xf>(v);   // row_shr:1
    v = dpp_add<0x112, 0xf>(v);   // row_shr:2
    v = dpp_add<0x114, 0xf>(v);   // row_shr:4
    v = dpp_add<0x118, 0xf>(v);   // row_shr:8
    v = dpp_add<0x142, 0xa>(v);   // row_bcast:15 -> rows 1,3
    v = dpp_add<0x143, 0xc>(v);   // row_bcast:31 -> rows 2,3
    return __int_as_float(__builtin_amdgcn_readlane(__float_as_int(v), 63));
}
template<int CTRL, int RMASK>
__device__ __forceinline__ unsigned dpp_min(unsigned v){
    unsigned r = (unsigned)__builtin_amdgcn_update_dpp((int)v, (int)v, CTRL, RMASK, 0xf, false);
    return v < r ? v : r;
}
__device__ __forceinline__ unsigned wave_umin(unsigned v){
    v = dpp_min<0x111, 0xf>(v);
    v = dpp_min<0x112, 0xf>(v);
    v = dpp_min<0x114, 0xf>(v);
    v = dpp_min<0x118, 0xf>(v);
    v = dpp_min<0x142, 0xa>(v);
    v = dpp_min<0x143, 0xc>(v);
    return (unsigned)__builtin_amdgcn_readlane((int)v, 63);
}

// ================= L1: embedding + QKV + task build + WIH transpose =================
// block = batch b (256 blocks x 512 threads)
__global__ __launch_bounds__(512) void embed_tasks(
    const float* __restrict__ src,
    const float* __restrict__ w1w, const float* __restrict__ w1b,
    const float* __restrict__ w2w, const float* __restrict__ w2b,
    const float* __restrict__ meta,
    const float* __restrict__ Wq, const float* __restrict__ bq,
    const float* __restrict__ Wk, const float* __restrict__ bk,
    const float* __restrict__ Wv, const float* __restrict__ bv,
    const float* __restrict__ wih, float* __restrict__ WIHT,
    float* __restrict__ X, float* __restrict__ Q,
    float* __restrict__ K, float* __restrict__ V,
    int* __restrict__ TASKS, int* __restrict__ ROWMAP, int* __restrict__ NT)
{
    __shared__ int sbuck[TT];
    int b = blockIdx.x;
    int t = threadIdx.x;

    // grid-stride WIH transpose (independent work, uses all threads)
    for (int idx = blockIdx.x*512 + threadIdx.x; idx < G3*HID; idx += 256*512){
        int o = idx / HID, i = idx % HID;
        WIHT[i*G3 + o] = wih[idx];
    }

    if (t < TT){
        int w = t / FEAT, f = t % FEAT;
        float s = src[(w*BATCH + b)*FEAT + f];
        float h1[EMBD], h2[EMBD];
        #pragma unroll
        for (int i=0;i<EMBD;i++) h1[i] = leakyf(s*w1w[f*EMBD+i] + w1b[f*EMBD+i]);
        #pragma unroll
        for (int j=0;j<EMBD;j++){
            float a = 0.f;
            #pragma unroll
            for (int i=0;i<EMBD;i++) a += h1[i]*w2w[(f*EMBD+j)*EMBD+i];
            h2[j] = a + w2b[f*EMBD+j];
        }
        float z[EMBD];
        float m = -INFINITY; int jm = 0;
        #pragma unroll
        for (int j=0;j<EMBD;j++){
            z[j] = (h2[j] + 0.5f*h1[j]) * 1e+05f;
            if (z[j] > m){ m = z[j]; jm = j; }
        }
        float se = 0.f;
        #pragma unroll
        for (int j=0;j<EMBD;j++){ z[j] = expf(z[j]-m); se += z[j]; }
        float inv = 1.0f / se;
        #pragma unroll
        for (int j=0;j<EMBD;j++) z[j] *= inv;
        sbuck[t] = jm;

        float xr[EMBD];
        #pragma unroll
        for (int e=0;e<EMBD;e++){
            float a = 0.f;
            #pragma unroll
            for (int i=0;i<EMBD;i++) a += z[i]*meta[(f*EMBD+i)*EMBD+e];
            xr[e] = a * 2.449489742783178f;
        }
        float* xp = X + (b*TT + t)*EMBD;
        float* qp = Q + (b*TT + t)*EMBD;
        float* kp = K + (b*TT + t)*EMBD;
        float* vp = V + (b*TT + t)*EMBD;
        #pragma unroll
        for (int e=0;e<EMBD;e++){
            xp[e] = xr[e];
            float aq=0.f, ak=0.f, av=0.f;
            #pragma unroll
            for (int i=0;i<EMBD;i++){
                aq += xr[i]*Wq[e*EMBD+i];
                ak += xr[i]*Wk[e*EMBD+i];
                av += xr[i]*Wv[e*EMBD+i];
            }
            qp[e] = aq + bq[e];
            kp[e] = ak + bk[e];
            vp[e] = av + bv[e];
        }
    }
    __syncthreads();
    // wave 0 builds the distinct-row task list for this batch
    if (threadIdx.x < 64){
        int f = threadIdx.x;
        unsigned mask = 0; int repw[6]; int cnt = 0;
        if (f < FEAT){
            #pragma unroll
            for (int w=0; w<WWIN; w++){
                int j = sbuck[w*FEAT + f];
                if (!((mask>>j) & 1u)){ mask |= 1u<<j; repw[j] = w; }
            }
            cnt = __popc(mask);
        }
        int inc = cnt;
        #pragma unroll
        for (int off=1; off<64; off<<=1){
            int n = __shfl_up(inc, off, 64);
            if (threadIdx.x >= off) inc += n;
        }
        int offset = inc - cnt;
        if (f < FEAT){
            int rk = 0;
            #pragma unroll
            for (int j=0;j<6;j++){
                if ((mask>>j) & 1u){
                    TASKS[b*MAXTASK + offset + rk] = (f<<8) | (j<<4) | repw[j];
                    rk++;
                }
            }
            #pragma unroll
            for (int w=0;w<WWIN;w++){
                int j = sbuck[w*FEAT + f];
                int r = __popc(mask & ((1u<<j)-1u));
                ROWMAP[b*TT + w*FEAT + f] = offset + r;
            }
        }
        if (threadIdx.x == 63) NT[b] = inc;
    }
}

// ================= L2: attention (distinct rows, count-ge descent, DPP reduce) =================
__global__ __launch_bounds__(256) void attn_topk(
    const float* __restrict__ Q, const float* __restrict__ K,
    const float* __restrict__ V, const int* __restrict__ TASKS,
    const int* __restrict__ NT, float2* __restrict__ OD)
{
    __shared__ float2 kk[512], vv[512];
    int blk = blockIdx.x;
    int b = blk / 3, h = blk % 3;
    const int base = b*TT*EMBD + 2*h;
    for (int t = threadIdx.x; t < 512; t += 256){
        if (t < TT){
            kk[t] = make_float2(K[base + t*EMBD], K[base + t*EMBD + 1]);
            vv[t] = make_float2(V[base + t*EMBD], V[base + t*EMBD + 1]);
        } else {
            kk[t] = make_float2(0.f, 0.f);
            vv[t] = make_float2(0.f, 0.f);
        }
    }
    __syncthreads();
    int nt = NT[b];
    int wave = threadIdx.x >> 6, lane = threadIdx.x & 63;
    const float SC = 0.7071067811865476f;
    for (int idx = blockIdx.y*4 + wave; idx < nt; idx += 16){
        int pk = TASKS[b*MAXTASK + idx];
        int rep_t = (pk & 15)*FEAT + (pk >> 8);
        float q0 = Q[base + rep_t*EMBD]     * SC;
        float q1 = Q[base + rep_t*EMBD + 1] * SC;

        float sv[8]; unsigned uk[8];
        #pragma unroll
        for (int i=0;i<8;i++){
            int j = lane + (i<<6);
            float2 kv = kk[j];
            float s = q0*kv.x + q1*kv.y;
            sv[i] = s;
            uk[i] = (j < TT) ? fkey(s) : 0u;
        }
        unsigned T = 0; int exact = 0;
        for (int bit = 31; bit >= 0; --bit){
            unsigned Tp = T | (1u<<bit);
            int c = 0;
            #pragma unroll
            for (int i=0;i<8;i++) c += __popcll(__ballot(uk[i] >= Tp));
            if (c >= TOPM) T = Tp;
            if (c == TOPM){ exact = 1; break; }
        }
        unsigned kth;
        if (exact){
            unsigned mn = 0xFFFFFFFFu;
            #pragma unroll
            for (int i=0;i<8;i++) mn = min(mn, (uk[i] >= T) ? uk[i] : 0xFFFFFFFFu);
            kth = wave_umin(mn);
        } else {
            kth = T;
        }
        float skth = fkey_inv(kth);
        float den=0.f, ox=0.f, oy=0.f;
        #pragma unroll
        for (int i=0;i<8;i++){
            float2 v2 = vv[lane + (i<<6)];
            float p = __expf(sv[i] - skth);
            p = (uk[i] >= kth) ? p : 0.f;
            den += p; ox += p*v2.x; oy += p*v2.y;
        }
        den = wave_fsum(den);
        ox  = wave_fsum(ox);
        oy  = wave_fsum(oy);
        if (lane == 0){
            float id = 1.0f/den;
            OD[(b*3 + h)*MAXTASK + idx] = make_float2(ox*id, oy*id);
        }
    }
}

// ================= L3: cooperative tail: post + GI + 8 GRU steps + FC =================
// grid 512 x 256. H kept TRANSPOSED: HT[i][b] (306 x 256) for coalesced GRU access.
__global__ __launch_bounds__(256) void coop_tail(
    const float* __restrict__ X, const float2* __restrict__ OD,
    const int* __restrict__ ROWMAP,
    const float* __restrict__ Wo, const float* __restrict__ bo,
    const float* __restrict__ l1s, const float* __restrict__ l1b,
    const float* __restrict__ fw1, const float* __restrict__ fb1,
    const float* __restrict__ fw2, const float* __restrict__ fb2,
    const float* __restrict__ l2s, const float* __restrict__ l2b,
    float* __restrict__ SEQ, const float* __restrict__ WIHT,
    const float* __restrict__ bih, float* __restrict__ GI,
    const float* __restrict__ whh, const float* __restrict__ bhh,
    const float* __restrict__ h0, float* __restrict__ HA, float* __restrict__ HB,
    const float* __restrict__ fcw, const float* __restrict__ fcb,
    float* __restrict__ out)
{
    cg::grid_group grid = cg::this_grid();
    __shared__ float smem[4*HID];   // G: 4x306 row tile; GRU: 3x306 weight rows

    // ---------- phase P: Wo + residual + LN1 + FFN + LN2 -> SEQ ----------
    for (int idx = blockIdx.x*256 + threadIdx.x; idx < BATCH*TT; idx += 512*256){
        int b = idx / TT, t = idx % TT;
        const float* xr = X + (b*TT + t)*EMBD;
        int rm = ROWMAP[b*TT + t];
        float orow[EMBD];
        #pragma unroll
        for (int h=0;h<3;h++){
            float2 od = OD[(b*3 + h)*MAXTASK + rm];
            orow[2*h]   = od.x;
            orow[2*h+1] = od.y;
        }
        float y[EMBD];
        #pragma unroll
        for (int e=0;e<EMBD;e++){
            float a = 0.f;
            #pragma unroll
            for (int e2=0;e2<EMBD;e2++) a += orow[e2]*Wo[e*EMBD+e2];
            y[e] = xr[e] + a + bo[e];
        }
        float mu=0.f;
        #pragma unroll
        for (int e=0;e<EMBD;e++) mu += y[e];
        mu *= (1.f/6.f);
        float var=0.f;
        #pragma unroll
        for (int e=0;e<EMBD;e++){ float d = y[e]-mu; var += d*d; }
        var *= (1.f/6.f);
        float isd = 1.0f / sqrtf(var + 1e-05f);
        float xn[EMBD];
        #pragma unroll
        for (int e=0;e<EMBD;e++) xn[e] = (y[e]-mu)*isd*l1s[e] + l1b[e];
        float hd[FFND];
        #pragma unroll
        for (int k=0;k<FFND;k++){
            float a = fb1[k];
            #pragma unroll
            for (int e=0;e<EMBD;e++) a += xn[e]*fw1[k*EMBD+e];
            hd[k] = fmaxf(a, 0.f);
        }
        float y2[EMBD];
        #pragma unroll
        for (int e=0;e<EMBD;e++){
            float a = fb2[e];
            #pragma unroll
            for (int k=0;k<FFND;k++) a += hd[k]*fw2[e*FFND+k];
            y2[e] = xn[e] + a;
        }
        float mu2=0.f;
        #pragma unroll
        for (int e=0;e<EMBD;e++) mu2 += y2[e];
        mu2 *= (1.f/6.f);
        float var2=0.f;
        #pragma unroll
        for (int e=0;e<EMBD;e++){ float d = y2[e]-mu2; var2 += d*d; }
        var2 *= (1.f/6.f);
        float isd2 = 1.0f / sqrtf(var2 + 1e-05f);
        int w = t / FEAT, ff = t % FEAT;
        float* dst = SEQ + (w*BATCH + b)*HID + ff*EMBD;
        #pragma unroll
        for (int e=0;e<EMBD;e++) dst[e] = (y2[e]-mu2)*isd2*l2s[e] + l2b[e];
    }
    grid.sync();

    // ---------- phase G: GI = SEQ(2048x306) @ WIHT(306x918) + bih ----------
    {
        int gy = blockIdx.x;                 // 0..511, 4 rows each
        for (int idx = threadIdx.x; idx < 4*HID; idx += 256){
            int r = idx / HID, i = idx % HID;
            smem[r*HID + i] = SEQ[(gy*4 + r)*HID + i];
        }
        __syncthreads();
        for (int c = threadIdx.x; c < G3; c += 256){
            float a0=0.f, a1=0.f, a2=0.f, a3=0.f;
            for (int i=0;i<HID;i++){
                float wv = WIHT[i*G3 + c];
                a0 += smem[i]*wv;
                a1 += smem[HID+i]*wv;
                a2 += smem[2*HID+i]*wv;
                a3 += smem[3*HID+i]*wv;
            }
            float bb = bih[c];
            GI[(gy*4+0)*G3 + c] = a0 + bb;
            GI[(gy*4+1)*G3 + c] = a1 + bb;
            GI[(gy*4+2)*G3 + c] = a2 + bb;
            GI[(gy*4+3)*G3 + c] = a3 + bb;
        }
    }
    grid.sync();

    // ---------- phase S: 8 GRU steps; HT layout [i][b] ----------
    for (int step = 0; step < 8; ++step){
        int j = blockIdx.x;
        if (j < HID){
            // stage whh rows j, 306+j, 612+j
            for (int idx = threadIdx.x; idx < 3*HID; idx += 256){
                int g = idx / HID, i = idx % HID;
                smem[g*HID + i] = whh[(g*HID + j)*HID + i];
            }
            __syncthreads();
            int b = threadIdx.x;
            const float* HTp = (step & 1) ? HA : HB;   // prev (transposed), unused for step 0
            float* HTn = (step & 1) ? HB : HA;
            float ar=0.f, az=0.f, an=0.f;
            float hj = 0.f;
            if (step == 0){
                const float* hrow = h0 + b*HID;
                for (int i=0;i<HID;i++){
                    float hv = hrow[i];
                    ar += hv*smem[i];
                    az += hv*smem[HID+i];
                    an += hv*smem[2*HID+i];
                }
                hj = hrow[j];
            } else {
                for (int i=0;i<HID;i++){
                    float hv = HTp[i*BATCH + b];
                    ar += hv*smem[i];
                    az += hv*smem[HID+i];
                    an += hv*smem[2*HID+i];
                }
                hj = HTp[j*BATCH + b];
            }
            const float* gi = GI + (step*BATCH + b)*G3;
            float rr = sigmf(gi[j]       + ar + bhh[j]);
            float zz = sigmf(gi[HID+j]   + az + bhh[HID+j]);
            float nn = tanhf(gi[2*HID+j] + rr*(an + bhh[2*HID+j]));
            HTn[j*BATCH + b] = (1.f - zz)*nn + zz*hj;
        }
        grid.sync();
    }

    // ---------- phase F: out = sigmoid(H @ fcw^T + fcb) ----------
    // final H is HTn of step 7: (7&1)=1 -> HB
    for (int idx = blockIdx.x*256 + threadIdx.x; idx < BATCH*FEAT; idx += 512*256){
        int b = idx / FEAT, f = idx % FEAT;
        float acc = 0.f;
        const float* wrow = fcw + f*HID;
        for (int i=0;i<HID;i++) acc += HB[i*BATCH + b]*wrow[i];
        out[b*FEAT + f] = sigmf(acc + fcb[f]);
    }
}

extern "C" void kernel_launch(void* const* d_in, const int* in_sizes, int n_in,
                              void* d_out, int out_size, void* d_ws, size_t ws_size,
                              hipStream_t stream)
{
    const float* src = (const float*)d_in[0];
    const float* w1w = (const float*)d_in[2];
    const float* w1b = (const float*)d_in[3];
    const float* w2w = (const float*)d_in[4];
    const float* w2b = (const float*)d_in[5];
    const float* meta= (const float*)d_in[6];
    const float* Wq = (const float*)d_in[7];  const float* bq = (const float*)d_in[8];
    const float* Wk = (const float*)d_in[9];  const float* bk = (const float*)d_in[10];
    const float* Wv = (const float*)d_in[11]; const float* bv = (const float*)d_in[12];
    const float* Wo = (const float*)d_in[13]; const float* bo = (const float*)d_in[14];
    const float* l1s= (const float*)d_in[15]; const float* l1b= (const float*)d_in[16];
    const float* fw1= (const float*)d_in[17]; const float* fb1= (const float*)d_in[18];
    const float* fw2= (const float*)d_in[19]; const float* fb2= (const float*)d_in[20];
    const float* l2s= (const float*)d_in[21]; const float* l2b= (const float*)d_in[22];
    const float* wih= (const float*)d_in[23]; const float* whh= (const float*)d_in[24];
    const float* bih= (const float*)d_in[25]; const float* bhh= (const float*)d_in[26];
    const float* h0 = (const float*)d_in[27];
    const float* fcw= (const float*)d_in[28]; const float* fcb= (const float*)d_in[29];

    float* ws = (float*)d_ws;
    float* X    = ws;                  // 705024
    float* Q    = X    + 705024;
    float* K    = Q    + 705024;
    float* V    = K    + 705024;
    float* SEQ  = V    + 705024;       // 705024
    float* GI   = SEQ  + 705024;       // 1880064
    float* HA   = GI   + 1880064;      // 78336 (transposed H)
    float* HB   = HA   + 78336;        // 78336
    float* WIHT = HB   + 78336;        // 280908
    float* ODf  = WIHT + 280908;       // 491520
    int*   TASKS= (int*)(ODf + 491520);    // 81920
    int*   RMAP = TASKS + 81920;           // 117504
    int*   NT   = RMAP + 117504;           // 256
    float2* OD  = (float2*)ODf;
    float* outp = (float*)d_out;

    embed_tasks<<<256, 512, 0, stream>>>(src, w1w, w1b, w2w, w2b, meta,
                                         Wq,bq,Wk,bk,Wv,bv, wih, WIHT,
                                         X,Q,K,V, TASKS, RMAP, NT);
    {
        dim3 g(768, 4);
        attn_topk<<<g, 256, 0, stream>>>(Q, K, V, TASKS, NT, OD);
    }
    {
        void* args[] = {
            (void*)&X, (void*)&OD, (void*)&RMAP,
            (void*)&Wo, (void*)&bo, (void*)&l1s, (void*)&l1b,
            (void*)&fw1, (void*)&fb1, (void*)&fw2, (void*)&fb2,
            (void*)&l2s, (void*)&l2b,
            (void*)&SEQ, (void*)&WIHT, (void*)&bih, (void*)&GI,
            (void*)&whh, (void*)&bhh, (void*)&h0, (void*)&HA, (void*)&HB,
            (void*)&fcw, (void*)&fcb, (void*)&outp
        };
        (void)hipLaunchCooperativeKernel((void*)coop_tail, dim3(512), dim3(256),
                                         args, 0, stream);
    }
}

// Round 7
// 399.683 us; speedup vs baseline: 2.1194x; 2.1194x over previous
//
#include <hip/hip_runtime.h>
#include <math.h>

#define WWIN 9
#define BATCH 256
#define FEAT 51
#define TT 459          // WWIN*FEAT
#define EMBD 6
#define HID 306
#define G3 918
#define FFND 12
#define TOPM 80
#define MAXTASK 320

__device__ __forceinline__ float leakyf(float v){ return v >= 0.f ? v : 0.01f*v; }
__device__ __forceinline__ float sigmf(float v){ return 1.f/(1.f+__expf(-v)); }

__device__ __forceinline__ unsigned fkey(float s){
    unsigned fb = __float_as_uint(s);
    unsigned m = (unsigned)((int)fb >> 31);
    return fb ^ (m | 0x80000000u);
}
__device__ __forceinline__ float fkey_inv(unsigned k){
    unsigned fb = (k & 0x80000000u) ? (k ^ 0x80000000u) : ~k;
    return __uint_as_float(fb);
}

// ---- DPP wave64 reductions (rocPRIM pattern); ctrl/mask constexpr via templates ----
template<int CTRL, int RMASK>
__device__ __forceinline__ float dpp_add(float v){
    int r = __builtin_amdgcn_update_dpp(0, __float_as_int(v), CTRL, RMASK, 0xf, true);
    return v + __int_as_float(r);
}
__device__ __forceinline__ float wave_fsum(float v){
    v = dpp_add<0x111, 0xf>(v);
    v = dpp_add<0x112, 0xf>(v);
    v = dpp_add<0x114, 0xf>(v);
    v = dpp_add<0x118, 0xf>(v);
    v = dpp_add<0x142, 0xa>(v);
    v = dpp_add<0x143, 0xc>(v);
    return __int_as_float(__builtin_amdgcn_readlane(__float_as_int(v), 63));
}
template<int CTRL, int RMASK>
__device__ __forceinline__ unsigned dpp_min(unsigned v){
    unsigned r = (unsigned)__builtin_amdgcn_update_dpp((int)v, (int)v, CTRL, RMASK, 0xf, false);
    return v < r ? v : r;
}
__device__ __forceinline__ unsigned wave_umin(unsigned v){
    v = dpp_min<0x111, 0xf>(v);
    v = dpp_min<0x112, 0xf>(v);
    v = dpp_min<0x114, 0xf>(v);
    v = dpp_min<0x118, 0xf>(v);
    v = dpp_min<0x142, 0xa>(v);
    v = dpp_min<0x143, 0xc>(v);
    return (unsigned)__builtin_amdgcn_readlane((int)v, 63);
}

// ================= L1: embedding + QKV + task build + weight transposes =================
__global__ __launch_bounds__(512) void embed_tasks(
    const float* __restrict__ src,
    const float* __restrict__ w1w, const float* __restrict__ w1b,
    const float* __restrict__ w2w, const float* __restrict__ w2b,
    const float* __restrict__ meta,
    const float* __restrict__ Wq, const float* __restrict__ bq,
    const float* __restrict__ Wk, const float* __restrict__ bk,
    const float* __restrict__ Wv, const float* __restrict__ bv,
    const float* __restrict__ wih, const float* __restrict__ whh,
    const float* __restrict__ fcw,
    float* __restrict__ WIHT, float* __restrict__ WHHT, float* __restrict__ FCNT,
    float* __restrict__ X, float* __restrict__ Q,
    float* __restrict__ K, float* __restrict__ V,
    int* __restrict__ TASKS, int* __restrict__ ROWMAP, int* __restrict__ NT)
{
    __shared__ int sbuck[TT];
    int b = blockIdx.x;
    int t = threadIdx.x;

    // grid-stride transposes (independent work)
    for (int idx = blockIdx.x*512 + threadIdx.x; idx < G3*HID; idx += 256*512){
        int o = idx / HID, i = idx % HID;
        WIHT[i*G3 + o] = wih[idx];
        WHHT[i*G3 + o] = whh[idx];
    }
    for (int idx = blockIdx.x*512 + threadIdx.x; idx < FEAT*HID; idx += 256*512){
        int f = idx / HID, i = idx % HID;
        FCNT[i*FEAT + f] = fcw[idx];
    }

    if (t < TT){
        int w = t / FEAT, f = t % FEAT;
        float s = src[(w*BATCH + b)*FEAT + f];
        float h1[EMBD], h2[EMBD];
        #pragma unroll
        for (int i=0;i<EMBD;i++) h1[i] = leakyf(s*w1w[f*EMBD+i] + w1b[f*EMBD+i]);
        #pragma unroll
        for (int j=0;j<EMBD;j++){
            float a = 0.f;
            #pragma unroll
            for (int i=0;i<EMBD;i++) a += h1[i]*w2w[(f*EMBD+j)*EMBD+i];
            h2[j] = a + w2b[f*EMBD+j];
        }
        float z[EMBD];
        float m = -INFINITY; int jm = 0;
        #pragma unroll
        for (int j=0;j<EMBD;j++){
            z[j] = (h2[j] + 0.5f*h1[j]) * 1e+05f;
            if (z[j] > m){ m = z[j]; jm = j; }
        }
        float se = 0.f;
        #pragma unroll
        for (int j=0;j<EMBD;j++){ z[j] = expf(z[j]-m); se += z[j]; }
        float inv = 1.0f / se;
        #pragma unroll
        for (int j=0;j<EMBD;j++) z[j] *= inv;
        sbuck[t] = jm;

        float xr[EMBD];
        #pragma unroll
        for (int e=0;e<EMBD;e++){
            float a = 0.f;
            #pragma unroll
            for (int i=0;i<EMBD;i++) a += z[i]*meta[(f*EMBD+i)*EMBD+e];
            xr[e] = a * 2.449489742783178f;
        }
        float* xp = X + (b*TT + t)*EMBD;
        float* qp = Q + (b*TT + t)*EMBD;
        float* kp = K + (b*TT + t)*EMBD;
        float* vp = V + (b*TT + t)*EMBD;
        #pragma unroll
        for (int e=0;e<EMBD;e++){
            xp[e] = xr[e];
            float aq=0.f, ak=0.f, av=0.f;
            #pragma unroll
            for (int i=0;i<EMBD;i++){
                aq += xr[i]*Wq[e*EMBD+i];
                ak += xr[i]*Wk[e*EMBD+i];
                av += xr[i]*Wv[e*EMBD+i];
            }
            qp[e] = aq + bq[e];
            kp[e] = ak + bk[e];
            vp[e] = av + bv[e];
        }
    }
    __syncthreads();
    if (threadIdx.x < 64){
        int f = threadIdx.x;
        unsigned mask = 0; int repw[6]; int cnt = 0;
        if (f < FEAT){
            #pragma unroll
            for (int w=0; w<WWIN; w++){
                int j = sbuck[w*FEAT + f];
                if (!((mask>>j) & 1u)){ mask |= 1u<<j; repw[j] = w; }
            }
            cnt = __popc(mask);
        }
        int inc = cnt;
        #pragma unroll
        for (int off=1; off<64; off<<=1){
            int n = __shfl_up(inc, off, 64);
            if (threadIdx.x >= off) inc += n;
        }
        int offset = inc - cnt;
        if (f < FEAT){
            int rk = 0;
            #pragma unroll
            for (int j=0;j<6;j++){
                if ((mask>>j) & 1u){
                    TASKS[b*MAXTASK + offset + rk] = (f<<8) | (j<<4) | repw[j];
                    rk++;
                }
            }
            #pragma unroll
            for (int w=0;w<WWIN;w++){
                int j = sbuck[w*FEAT + f];
                int r = __popc(mask & ((1u<<j)-1u));
                ROWMAP[b*TT + w*FEAT + f] = offset + r;
            }
        }
        if (threadIdx.x == 63) NT[b] = inc;
    }
}

// ================= L2: attention (distinct rows, count-ge descent, DPP reduce) =================
__global__ __launch_bounds__(256) void attn_topk(
    const float* __restrict__ Q, const float* __restrict__ K,
    const float* __restrict__ V, const int* __restrict__ TASKS,
    const int* __restrict__ NT, float2* __restrict__ OD)
{
    __shared__ float2 kk[512], vv[512];
    int blk = blockIdx.x;
    int b = blk / 3, h = blk % 3;
    const int base = b*TT*EMBD + 2*h;
    for (int t = threadIdx.x; t < 512; t += 256){
        if (t < TT){
            kk[t] = make_float2(K[base + t*EMBD], K[base + t*EMBD + 1]);
            vv[t] = make_float2(V[base + t*EMBD], V[base + t*EMBD + 1]);
        } else {
            kk[t] = make_float2(0.f, 0.f);
            vv[t] = make_float2(0.f, 0.f);
        }
    }
    __syncthreads();
    int nt = NT[b];
    int wave = threadIdx.x >> 6, lane = threadIdx.x & 63;
    const float SC = 0.7071067811865476f;
    for (int idx = blockIdx.y*4 + wave; idx < nt; idx += 16){
        int pk = TASKS[b*MAXTASK + idx];
        int rep_t = (pk & 15)*FEAT + (pk >> 8);
        float q0 = Q[base + rep_t*EMBD]     * SC;
        float q1 = Q[base + rep_t*EMBD + 1] * SC;

        float sv[8]; unsigned uk[8];
        #pragma unroll
        for (int i=0;i<8;i++){
            int j = lane + (i<<6);
            float2 kv = kk[j];
            float s = q0*kv.x + q1*kv.y;
            sv[i] = s;
            uk[i] = (j < TT) ? fkey(s) : 0u;
        }
        unsigned T = 0; int exact = 0;
        for (int bit = 31; bit >= 0; --bit){
            unsigned Tp = T | (1u<<bit);
            int c = 0;
            #pragma unroll
            for (int i=0;i<8;i++) c += __popcll(__ballot(uk[i] >= Tp));
            if (c >= TOPM) T = Tp;
            if (c == TOPM){ exact = 1; break; }
        }
        unsigned kth;
        if (exact){
            unsigned mn = 0xFFFFFFFFu;
            #pragma unroll
            for (int i=0;i<8;i++) mn = min(mn, (uk[i] >= T) ? uk[i] : 0xFFFFFFFFu);
            kth = wave_umin(mn);
        } else {
            kth = T;
        }
        float skth = fkey_inv(kth);
        float den=0.f, ox=0.f, oy=0.f;
        #pragma unroll
        for (int i=0;i<8;i++){
            float2 v2 = vv[lane + (i<<6)];
            float p = __expf(sv[i] - skth);
            p = (uk[i] >= kth) ? p : 0.f;
            den += p; ox += p*v2.x; oy += p*v2.y;
        }
        den = wave_fsum(den);
        ox  = wave_fsum(ox);
        oy  = wave_fsum(oy);
        if (lane == 0){
            float id = 1.0f/den;
            OD[(b*3 + h)*MAXTASK + idx] = make_float2(ox*id, oy*id);
        }
    }
}

// ================= L3: post-block fused into GI matmul (SEQ lives in LDS only) =================
// grid (4, 256): gx = 256-col slice of 918, gy = 8-row group of the 2048 SEQ rows.
__global__ __launch_bounds__(256) void post_gi(
    const float* __restrict__ X, const float2* __restrict__ OD,
    const int* __restrict__ ROWMAP,
    const float* __restrict__ Wo, const float* __restrict__ bo,
    const float* __restrict__ l1s, const float* __restrict__ l1b,
    const float* __restrict__ fw1, const float* __restrict__ fb1,
    const float* __restrict__ fw2, const float* __restrict__ fb2,
    const float* __restrict__ l2s, const float* __restrict__ l2b,
    const float* __restrict__ WIHT, const float* __restrict__ bih,
    float* __restrict__ GI)
{
    __shared__ float sL[8][HID];
    int gy = blockIdx.y, gx = blockIdx.x;
    // build 8 SEQ rows: row r = gy*8+k  <->  (w = r/256, b = r%256)
    for (int idx = threadIdx.x; idx < 8*FEAT; idx += 256){
        int k = idx / FEAT, ff = idx % FEAT;
        int r = gy*8 + k;
        int w = r >> 8, b = r & 255;
        int t = w*FEAT + ff;
        const float* xr = X + (b*TT + t)*EMBD;
        int rm = ROWMAP[b*TT + t];
        float orow[EMBD];
        #pragma unroll
        for (int h=0;h<3;h++){
            float2 od = OD[(b*3 + h)*MAXTASK + rm];
            orow[2*h]   = od.x;
            orow[2*h+1] = od.y;
        }
        float y[EMBD];
        #pragma unroll
        for (int e=0;e<EMBD;e++){
            float a = 0.f;
            #pragma unroll
            for (int e2=0;e2<EMBD;e2++) a += orow[e2]*Wo[e*EMBD+e2];
            y[e] = xr[e] + a + bo[e];
        }
        float mu=0.f;
        #pragma unroll
        for (int e=0;e<EMBD;e++) mu += y[e];
        mu *= (1.f/6.f);
        float var=0.f;
        #pragma unroll
        for (int e=0;e<EMBD;e++){ float d = y[e]-mu; var += d*d; }
        var *= (1.f/6.f);
        float isd = 1.0f / sqrtf(var + 1e-05f);
        float xn[EMBD];
        #pragma unroll
        for (int e=0;e<EMBD;e++) xn[e] = (y[e]-mu)*isd*l1s[e] + l1b[e];
        float hd[FFND];
        #pragma unroll
        for (int kk2=0;kk2<FFND;kk2++){
            float a = fb1[kk2];
            #pragma unroll
            for (int e=0;e<EMBD;e++) a += xn[e]*fw1[kk2*EMBD+e];
            hd[kk2] = fmaxf(a, 0.f);
        }
        float y2[EMBD];
        #pragma unroll
        for (int e=0;e<EMBD;e++){
            float a = fb2[e];
            #pragma unroll
            for (int kk2=0;kk2<FFND;kk2++) a += hd[kk2]*fw2[e*FFND+kk2];
            y2[e] = xn[e] + a;
        }
        float mu2=0.f;
        #pragma unroll
        for (int e=0;e<EMBD;e++) mu2 += y2[e];
        mu2 *= (1.f/6.f);
        float var2=0.f;
        #pragma unroll
        for (int e=0;e<EMBD;e++){ float d = y2[e]-mu2; var2 += d*d; }
        var2 *= (1.f/6.f);
        float isd2 = 1.0f / sqrtf(var2 + 1e-05f);
        #pragma unroll
        for (int e=0;e<EMBD;e++) sL[k][ff*EMBD+e] = (y2[e]-mu2)*isd2*l2s[e] + l2b[e];
    }
    __syncthreads();
    int col = gx*256 + threadIdx.x;
    if (col >= G3) return;
    float acc[8];
    #pragma unroll
    for (int k=0;k<8;k++) acc[k] = 0.f;
    for (int i=0;i<HID;i++){
        float wv = WIHT[i*G3 + col];
        #pragma unroll
        for (int k=0;k<8;k++) acc[k] += sL[k][i]*wv;
    }
    float bb = bih[col];
    #pragma unroll
    for (int k=0;k<8;k++) GI[(size_t)(gy*8+k)*G3 + col] = acc[k] + bb;
}

// ================= L4: all 8 GRU steps + final FC, 4 batches per block =================
// 64 blocks x 256 threads. h in LDS; gh exchanged via stride-5-padded LDS.
__global__ __launch_bounds__(256) void gru_fcn(
    const float* __restrict__ GI, const float* __restrict__ WHHT,
    const float* __restrict__ bhh, const float* __restrict__ h0,
    const float* __restrict__ FCNT, const float* __restrict__ fcb,
    float* __restrict__ out)
{
    __shared__ float hL[4][HID];
    __shared__ float gh[G3*5];   // [c*5 + bb], stride 5 kills bank conflicts
    int b0 = blockIdx.x*4;
    int tid = threadIdx.x;
    for (int idx = tid; idx < 4*HID; idx += 256)
        hL[idx/HID][idx%HID] = h0[(size_t)(b0 + idx/HID)*HID + idx%HID];
    __syncthreads();
    int c0 = tid, c1 = tid+256, c2 = tid+512, c3 = tid+768;
    bool has3 = (c3 < G3);
    for (int step = 0; step < 8; ++step){
        float a0[4], a1[4], a2[4], a3[4];
        #pragma unroll
        for (int q=0;q<4;q++){ a0[q]=0.f; a1[q]=0.f; a2[q]=0.f; a3[q]=0.f; }
        for (int i=0;i<HID;i++){
            const float* wr = WHHT + (size_t)i*G3;
            float w0 = wr[c0], w1 = wr[c1], w2 = wr[c2];
            float w3 = has3 ? wr[c3] : 0.f;
            float hv0 = hL[0][i], hv1 = hL[1][i], hv2 = hL[2][i], hv3 = hL[3][i];
            a0[0] += w0*hv0; a0[1] += w0*hv1; a0[2] += w0*hv2; a0[3] += w0*hv3;
            a1[0] += w1*hv0; a1[1] += w1*hv1; a1[2] += w1*hv2; a1[3] += w1*hv3;
            a2[0] += w2*hv0; a2[1] += w2*hv1; a2[2] += w2*hv2; a2[3] += w2*hv3;
            a3[0] += w3*hv0; a3[1] += w3*hv1; a3[2] += w3*hv2; a3[3] += w3*hv3;
        }
        #pragma unroll
        for (int q=0;q<4;q++){
            gh[c0*5+q] = a0[q];
            gh[c1*5+q] = a1[q];
            gh[c2*5+q] = a2[q];
            if (has3) gh[c3*5+q] = a3[q];
        }
        __syncthreads();
        for (int j = tid; j < HID; j += 256){
            float br = bhh[j], bz = bhh[HID+j], bn = bhh[2*HID+j];
            #pragma unroll
            for (int q=0;q<4;q++){
                const float* gi = GI + ((size_t)step*BATCH + (b0+q))*G3;
                float rr = sigmf(gi[j]       + gh[j*5+q]         + br);
                float zz = sigmf(gi[HID+j]   + gh[(HID+j)*5+q]   + bz);
                float nn = tanhf(gi[2*HID+j] + rr*(gh[(2*HID+j)*5+q] + bn));
                hL[q][j] = (1.f - zz)*nn + zz*hL[q][j];
            }
        }
        __syncthreads();
    }
    // final FC + sigmoid: 4*51 = 204 tasks
    if (tid < 4*FEAT){
        int q = tid / FEAT, f = tid % FEAT;
        float acc = 0.f;
        for (int i=0;i<HID;i++) acc += hL[q][i]*FCNT[i*FEAT+f];
        out[(size_t)(b0+q)*FEAT + f] = sigmf(acc + fcb[f]);
    }
}

extern "C" void kernel_launch(void* const* d_in, const int* in_sizes, int n_in,
                              void* d_out, int out_size, void* d_ws, size_t ws_size,
                              hipStream_t stream)
{
    const float* src = (const float*)d_in[0];
    const float* w1w = (const float*)d_in[2];
    const float* w1b = (const float*)d_in[3];
    const float* w2w = (const float*)d_in[4];
    const float* w2b = (const float*)d_in[5];
    const float* meta= (const float*)d_in[6];
    const float* Wq = (const float*)d_in[7];  const float* bq = (const float*)d_in[8];
    const float* Wk = (const float*)d_in[9];  const float* bk = (const float*)d_in[10];
    const float* Wv = (const float*)d_in[11]; const float* bv = (const float*)d_in[12];
    const float* Wo = (const float*)d_in[13]; const float* bo = (const float*)d_in[14];
    const float* l1s= (const float*)d_in[15]; const float* l1b= (const float*)d_in[16];
    const float* fw1= (const float*)d_in[17]; const float* fb1= (const float*)d_in[18];
    const float* fw2= (const float*)d_in[19]; const float* fb2= (const float*)d_in[20];
    const float* l2s= (const float*)d_in[21]; const float* l2b= (const float*)d_in[22];
    const float* wih= (const float*)d_in[23]; const float* whh= (const float*)d_in[24];
    const float* bih= (const float*)d_in[25]; const float* bhh= (const float*)d_in[26];
    const float* h0 = (const float*)d_in[27];
    const float* fcw= (const float*)d_in[28]; const float* fcb= (const float*)d_in[29];

    float* ws = (float*)d_ws;
    float* X    = ws;                  // 705024
    float* Q    = X    + 705024;
    float* K    = Q    + 705024;
    float* V    = K    + 705024;
    float* GI   = V    + 705024;       // 1880064
    float* WIHT = GI   + 1880064;      // 280908
    float* WHHT = WIHT + 280908;       // 280908
    float* FCNT = WHHT + 280908;       // 15606
    float* ODf  = FCNT + 15606;        // 491520
    int*   TASKS= (int*)(ODf + 491520);    // 81920
    int*   RMAP = TASKS + 81920;           // 117504
    int*   NT   = RMAP + 117504;           // 256
    float2* OD  = (float2*)ODf;
    float* outp = (float*)d_out;

    embed_tasks<<<256, 512, 0, stream>>>(src, w1w, w1b, w2w, w2b, meta,
                                         Wq,bq,Wk,bk,Wv,bv, wih, whh, fcw,
                                         WIHT, WHHT, FCNT,
                                         X,Q,K,V, TASKS, RMAP, NT);
    {
        dim3 g(768, 4);
        attn_topk<<<g, 256, 0, stream>>>(Q, K, V, TASKS, NT, OD);
    }
    {
        dim3 g(4, 256);
        post_gi<<<g, 256, 0, stream>>>(X, OD, RMAP, Wo, bo, l1s, l1b,
                                       fw1, fb1, fw2, fb2, l2s, l2b,
                                       WIHT, bih, GI);
    }
    gru_fcn<<<64, 256, 0, stream>>>(GI, WHHT, bhh, h0, FCNT, fcb, outp);
}

// Round 8
// 372.805 us; speedup vs baseline: 2.2722x; 1.0721x over previous
//
#include <hip/hip_runtime.h>
#include <math.h>

#define WWIN 9
#define BATCH 256
#define FEAT 51
#define TT 459          // WWIN*FEAT
#define EMBD 6
#define HID 306
#define G3 918
#define FFND 12
#define TOPM 80
#define MAXTASK 320

__device__ __forceinline__ float leakyf(float v){ return v >= 0.f ? v : 0.01f*v; }
__device__ __forceinline__ float sigmf(float v){ return 1.f/(1.f+__expf(-v)); }

__device__ __forceinline__ unsigned fkey(float s){
    unsigned fb = __float_as_uint(s);
    unsigned m = (unsigned)((int)fb >> 31);
    return fb ^ (m | 0x80000000u);
}
__device__ __forceinline__ float fkey_inv(unsigned k){
    unsigned fb = (k & 0x80000000u) ? (k ^ 0x80000000u) : ~k;
    return __uint_as_float(fb);
}

// ---- DPP wave64 reductions (rocPRIM pattern); ctrl/mask constexpr via templates ----
template<int CTRL, int RMASK>
__device__ __forceinline__ float dpp_add(float v){
    int r = __builtin_amdgcn_update_dpp(0, __float_as_int(v), CTRL, RMASK, 0xf, true);
    return v + __int_as_float(r);
}
__device__ __forceinline__ float wave_fsum(float v){
    v = dpp_add<0x111, 0xf>(v);
    v = dpp_add<0x112, 0xf>(v);
    v = dpp_add<0x114, 0xf>(v);
    v = dpp_add<0x118, 0xf>(v);
    v = dpp_add<0x142, 0xa>(v);
    v = dpp_add<0x143, 0xc>(v);
    return __int_as_float(__builtin_amdgcn_readlane(__float_as_int(v), 63));
}
template<int CTRL, int RMASK>
__device__ __forceinline__ unsigned dpp_min(unsigned v){
    unsigned r = (unsigned)__builtin_amdgcn_update_dpp((int)v, (int)v, CTRL, RMASK, 0xf, false);
    return v < r ? v : r;
}
__device__ __forceinline__ unsigned wave_umin(unsigned v){
    v = dpp_min<0x111, 0xf>(v);
    v = dpp_min<0x112, 0xf>(v);
    v = dpp_min<0x114, 0xf>(v);
    v = dpp_min<0x118, 0xf>(v);
    v = dpp_min<0x142, 0xa>(v);
    v = dpp_min<0x143, 0xc>(v);
    return (unsigned)__builtin_amdgcn_readlane((int)v, 63);
}

// ================= L1: embedding + QKV + task build + weight transposes =================
__global__ __launch_bounds__(512) void embed_tasks(
    const float* __restrict__ src,
    const float* __restrict__ w1w, const float* __restrict__ w1b,
    const float* __restrict__ w2w, const float* __restrict__ w2b,
    const float* __restrict__ meta,
    const float* __restrict__ Wq, const float* __restrict__ bq,
    const float* __restrict__ Wk, const float* __restrict__ bk,
    const float* __restrict__ Wv, const float* __restrict__ bv,
    const float* __restrict__ wih, const float* __restrict__ whh,
    const float* __restrict__ fcw,
    float* __restrict__ WIHT, float* __restrict__ WHHT, float* __restrict__ FCNT,
    float* __restrict__ X, float* __restrict__ Q,
    float* __restrict__ K, float* __restrict__ V,
    int* __restrict__ TASKS, int* __restrict__ ROWMAP, int* __restrict__ NT)
{
    __shared__ int sbuck[TT];
    int b = blockIdx.x;
    int t = threadIdx.x;

    // grid-stride transposes (independent work)
    for (int idx = blockIdx.x*512 + threadIdx.x; idx < G3*HID; idx += 256*512){
        int o = idx / HID, i = idx % HID;
        WIHT[i*G3 + o] = wih[idx];
        WHHT[i*G3 + o] = whh[idx];
    }
    for (int idx = blockIdx.x*512 + threadIdx.x; idx < FEAT*HID; idx += 256*512){
        int f = idx / HID, i = idx % HID;
        FCNT[i*FEAT + f] = fcw[idx];
    }

    if (t < TT){
        int w = t / FEAT, f = t % FEAT;
        float s = src[(w*BATCH + b)*FEAT + f];
        float h1[EMBD], h2[EMBD];
        #pragma unroll
        for (int i=0;i<EMBD;i++) h1[i] = leakyf(s*w1w[f*EMBD+i] + w1b[f*EMBD+i]);
        #pragma unroll
        for (int j=0;j<EMBD;j++){
            float a = 0.f;
            #pragma unroll
            for (int i=0;i<EMBD;i++) a += h1[i]*w2w[(f*EMBD+j)*EMBD+i];
            h2[j] = a + w2b[f*EMBD+j];
        }
        float z[EMBD];
        float m = -INFINITY; int jm = 0;
        #pragma unroll
        for (int j=0;j<EMBD;j++){
            z[j] = (h2[j] + 0.5f*h1[j]) * 1e+05f;
            if (z[j] > m){ m = z[j]; jm = j; }
        }
        float se = 0.f;
        #pragma unroll
        for (int j=0;j<EMBD;j++){ z[j] = expf(z[j]-m); se += z[j]; }
        float inv = 1.0f / se;
        #pragma unroll
        for (int j=0;j<EMBD;j++) z[j] *= inv;
        sbuck[t] = jm;

        float xr[EMBD];
        #pragma unroll
        for (int e=0;e<EMBD;e++){
            float a = 0.f;
            #pragma unroll
            for (int i=0;i<EMBD;i++) a += z[i]*meta[(f*EMBD+i)*EMBD+e];
            xr[e] = a * 2.449489742783178f;
        }
        float* xp = X + (b*TT + t)*EMBD;
        float* qp = Q + (b*TT + t)*EMBD;
        float* kp = K + (b*TT + t)*EMBD;
        float* vp = V + (b*TT + t)*EMBD;
        #pragma unroll
        for (int e=0;e<EMBD;e++){
            xp[e] = xr[e];
            float aq=0.f, ak=0.f, av=0.f;
            #pragma unroll
            for (int i=0;i<EMBD;i++){
                aq += xr[i]*Wq[e*EMBD+i];
                ak += xr[i]*Wk[e*EMBD+i];
                av += xr[i]*Wv[e*EMBD+i];
            }
            qp[e] = aq + bq[e];
            kp[e] = ak + bk[e];
            vp[e] = av + bv[e];
        }
    }
    __syncthreads();
    if (threadIdx.x < 64){
        int f = threadIdx.x;
        unsigned mask = 0; int repw[6]; int cnt = 0;
        if (f < FEAT){
            #pragma unroll
            for (int w=0; w<WWIN; w++){
                int j = sbuck[w*FEAT + f];
                if (!((mask>>j) & 1u)){ mask |= 1u<<j; repw[j] = w; }
            }
            cnt = __popc(mask);
        }
        int inc = cnt;
        #pragma unroll
        for (int off=1; off<64; off<<=1){
            int n = __shfl_up(inc, off, 64);
            if (threadIdx.x >= off) inc += n;
        }
        int offset = inc - cnt;
        if (f < FEAT){
            int rk = 0;
            #pragma unroll
            for (int j=0;j<6;j++){
                if ((mask>>j) & 1u){
                    TASKS[b*MAXTASK + offset + rk] = (f<<8) | (j<<4) | repw[j];
                    rk++;
                }
            }
            #pragma unroll
            for (int w=0;w<WWIN;w++){
                int j = sbuck[w*FEAT + f];
                int r = __popc(mask & ((1u<<j)-1u));
                ROWMAP[b*TT + w*FEAT + f] = offset + r;
            }
        }
        if (threadIdx.x == 63) NT[b] = inc;
    }
}

// ================= L2: attention (distinct rows, count-ge descent, DPP reduce) =================
__global__ __launch_bounds__(256) void attn_topk(
    const float* __restrict__ Q, const float* __restrict__ K,
    const float* __restrict__ V, const int* __restrict__ TASKS,
    const int* __restrict__ NT, float2* __restrict__ OD)
{
    __shared__ float2 kk[512], vv[512];
    int blk = blockIdx.x;
    int b = blk / 3, h = blk % 3;
    const int base = b*TT*EMBD + 2*h;
    for (int t = threadIdx.x; t < 512; t += 256){
        if (t < TT){
            kk[t] = make_float2(K[base + t*EMBD], K[base + t*EMBD + 1]);
            vv[t] = make_float2(V[base + t*EMBD], V[base + t*EMBD + 1]);
        } else {
            kk[t] = make_float2(0.f, 0.f);
            vv[t] = make_float2(0.f, 0.f);
        }
    }
    __syncthreads();
    int nt = NT[b];
    int wave = threadIdx.x >> 6, lane = threadIdx.x & 63;
    const float SC = 0.7071067811865476f;
    for (int idx = blockIdx.y*4 + wave; idx < nt; idx += 16){
        int pk = TASKS[b*MAXTASK + idx];
        int rep_t = (pk & 15)*FEAT + (pk >> 8);
        float q0 = Q[base + rep_t*EMBD]     * SC;
        float q1 = Q[base + rep_t*EMBD + 1] * SC;

        float sv[8]; unsigned uk[8];
        #pragma unroll
        for (int i=0;i<8;i++){
            int j = lane + (i<<6);
            float2 kv = kk[j];
            float s = q0*kv.x + q1*kv.y;
            sv[i] = s;
            uk[i] = (j < TT) ? fkey(s) : 0u;
        }
        unsigned T = 0; int exact = 0;
        for (int bit = 31; bit >= 0; --bit){
            unsigned Tp = T | (1u<<bit);
            int c = 0;
            #pragma unroll
            for (int i=0;i<8;i++) c += __popcll(__ballot(uk[i] >= Tp));
            if (c >= TOPM) T = Tp;
            if (c == TOPM){ exact = 1; break; }
        }
        unsigned kth;
        if (exact){
            unsigned mn = 0xFFFFFFFFu;
            #pragma unroll
            for (int i=0;i<8;i++) mn = min(mn, (uk[i] >= T) ? uk[i] : 0xFFFFFFFFu);
            kth = wave_umin(mn);
        } else {
            kth = T;
        }
        float skth = fkey_inv(kth);
        float den=0.f, ox=0.f, oy=0.f;
        #pragma unroll
        for (int i=0;i<8;i++){
            float2 v2 = vv[lane + (i<<6)];
            float p = __expf(sv[i] - skth);
            p = (uk[i] >= kth) ? p : 0.f;
            den += p; ox += p*v2.x; oy += p*v2.y;
        }
        den = wave_fsum(den);
        ox  = wave_fsum(ox);
        oy  = wave_fsum(oy);
        if (lane == 0){
            float id = 1.0f/den;
            OD[(b*3 + h)*MAXTASK + idx] = make_float2(ox*id, oy*id);
        }
    }
}

// ================= L3: post-block fused into GI matmul (SEQ lives in LDS only) =================
__global__ __launch_bounds__(256) void post_gi(
    const float* __restrict__ X, const float2* __restrict__ OD,
    const int* __restrict__ ROWMAP,
    const float* __restrict__ Wo, const float* __restrict__ bo,
    const float* __restrict__ l1s, const float* __restrict__ l1b,
    const float* __restrict__ fw1, const float* __restrict__ fb1,
    const float* __restrict__ fw2, const float* __restrict__ fb2,
    const float* __restrict__ l2s, const float* __restrict__ l2b,
    const float* __restrict__ WIHT, const float* __restrict__ bih,
    float* __restrict__ GI)
{
    __shared__ float sL[8][HID];
    int gy = blockIdx.y, gx = blockIdx.x;
    for (int idx = threadIdx.x; idx < 8*FEAT; idx += 256){
        int k = idx / FEAT, ff = idx % FEAT;
        int r = gy*8 + k;
        int w = r >> 8, b = r & 255;
        int t = w*FEAT + ff;
        const float* xr = X + (b*TT + t)*EMBD;
        int rm = ROWMAP[b*TT + t];
        float orow[EMBD];
        #pragma unroll
        for (int h=0;h<3;h++){
            float2 od = OD[(b*3 + h)*MAXTASK + rm];
            orow[2*h]   = od.x;
            orow[2*h+1] = od.y;
        }
        float y[EMBD];
        #pragma unroll
        for (int e=0;e<EMBD;e++){
            float a = 0.f;
            #pragma unroll
            for (int e2=0;e2<EMBD;e2++) a += orow[e2]*Wo[e*EMBD+e2];
            y[e] = xr[e] + a + bo[e];
        }
        float mu=0.f;
        #pragma unroll
        for (int e=0;e<EMBD;e++) mu += y[e];
        mu *= (1.f/6.f);
        float var=0.f;
        #pragma unroll
        for (int e=0;e<EMBD;e++){ float d = y[e]-mu; var += d*d; }
        var *= (1.f/6.f);
        float isd = 1.0f / sqrtf(var + 1e-05f);
        float xn[EMBD];
        #pragma unroll
        for (int e=0;e<EMBD;e++) xn[e] = (y[e]-mu)*isd*l1s[e] + l1b[e];
        float hd[FFND];
        #pragma unroll
        for (int kk2=0;kk2<FFND;kk2++){
            float a = fb1[kk2];
            #pragma unroll
            for (int e=0;e<EMBD;e++) a += xn[e]*fw1[kk2*EMBD+e];
            hd[kk2] = fmaxf(a, 0.f);
        }
        float y2[EMBD];
        #pragma unroll
        for (int e=0;e<EMBD;e++){
            float a = fb2[e];
            #pragma unroll
            for (int kk2=0;kk2<FFND;kk2++) a += hd[kk2]*fw2[e*FFND+kk2];
            y2[e] = xn[e] + a;
        }
        float mu2=0.f;
        #pragma unroll
        for (int e=0;e<EMBD;e++) mu2 += y2[e];
        mu2 *= (1.f/6.f);
        float var2=0.f;
        #pragma unroll
        for (int e=0;e<EMBD;e++){ float d = y2[e]-mu2; var2 += d*d; }
        var2 *= (1.f/6.f);
        float isd2 = 1.0f / sqrtf(var2 + 1e-05f);
        #pragma unroll
        for (int e=0;e<EMBD;e++) sL[k][ff*EMBD+e] = (y2[e]-mu2)*isd2*l2s[e] + l2b[e];
    }
    __syncthreads();
    int col = gx*256 + threadIdx.x;
    if (col >= G3) return;
    float acc[8];
    #pragma unroll
    for (int k=0;k<8;k++) acc[k] = 0.f;
    for (int i=0;i<HID;i++){
        float wv = WIHT[i*G3 + col];
        #pragma unroll
        for (int k=0;k<8;k++) acc[k] += sL[k][i]*wv;
    }
    float bb = bih[col];
    #pragma unroll
    for (int k=0;k<8;k++) GI[(size_t)(gy*8+k)*G3 + col] = acc[k] + bb;
}

// ================= L4: GRU 8 steps + FC; thread j owns cols (j, 306+j, 612+j) =================
// 64 blocks x 320 threads, 4 batches/block. Register ping-pong weight prefetch.
#define PF 6   // rows per chunk; 306 = 6*51

#define LOADC(buf, i0_) { \
    _Pragma("unroll") \
    for (int r=0;r<PF;r++){ \
        const float* wp = WHHT + (size_t)((i0_)+r)*G3 + j; \
        buf[3*r] = wp[0]; buf[3*r+1] = wp[HID]; buf[3*r+2] = wp[2*HID]; \
    } }

#define COMPC(buf, i0_) { \
    _Pragma("unroll") \
    for (int r=0;r<PF;r++){ \
        float4 hv = *(const float4*)&hL[(i0_)+r][0]; \
        float wr_ = buf[3*r], wz_ = buf[3*r+1], wn_ = buf[3*r+2]; \
        ar[0] += wr_*hv.x; ar[1] += wr_*hv.y; ar[2] += wr_*hv.z; ar[3] += wr_*hv.w; \
        az[0] += wz_*hv.x; az[1] += wz_*hv.y; az[2] += wz_*hv.z; az[3] += wz_*hv.w; \
        an[0] += wn_*hv.x; an[1] += wn_*hv.y; an[2] += wn_*hv.z; an[3] += wn_*hv.w; \
    } }

__global__ __launch_bounds__(320) void gru_fcn(
    const float* __restrict__ GI, const float* __restrict__ WHHT,
    const float* __restrict__ bhh, const float* __restrict__ h0,
    const float* __restrict__ FCNT, const float* __restrict__ fcb,
    float* __restrict__ out)
{
    __shared__ float hL[HID][4];
    int b0 = blockIdx.x*4;
    int tid = threadIdx.x;
    for (int idx = tid; idx < 4*HID; idx += 320){
        int q = idx / HID, i = idx % HID;
        hL[i][q] = h0[(size_t)(b0+q)*HID + i];
    }
    __syncthreads();

    int j = tid;
    bool act = (j < HID);
    float br=0.f, bz=0.f, bn=0.f;
    if (act){ br = bhh[j]; bz = bhh[HID+j]; bn = bhh[2*HID+j]; }

    for (int step = 0; step < 8; ++step){
        // prefetch this step's input gates (independent of matmul)
        float gr[4], gz[4], gn[4];
        if (act){
            #pragma unroll
            for (int q=0;q<4;q++){
                const float* gi = GI + ((size_t)step*BATCH + b0 + q)*G3;
                gr[q] = gi[j]; gz[q] = gi[HID+j]; gn[q] = gi[2*HID+j];
            }
        }
        float ar[4]={0,0,0,0}, az[4]={0,0,0,0}, an[4]={0,0,0,0};
        float rwA[3*PF], rwB[3*PF];
        LOADC(rwA, 0);
        for (int p = 0; p < 25; ++p){
            int c0 = 2*p*PF;
            LOADC(rwB, c0 + PF);
            COMPC(rwA, c0);
            LOADC(rwA, c0 + 2*PF);
            COMPC(rwB, c0 + PF);
        }
        COMPC(rwA, 50*PF);
        __syncthreads();   // all matmul reads of hL done
        if (act){
            float4 hold = *(const float4*)&hL[j][0];
            float hnew[4];
            #pragma unroll
            for (int q=0;q<4;q++){
                float rr = sigmf(gr[q] + ar[q] + br);
                float zz = sigmf(gz[q] + az[q] + bz);
                float nn = tanhf(gn[q] + rr*(an[q] + bn));
                float hp = (q==0)?hold.x:(q==1)?hold.y:(q==2)?hold.z:hold.w;
                hnew[q] = (1.f - zz)*nn + zz*hp;
            }
            float4 hv = make_float4(hnew[0], hnew[1], hnew[2], hnew[3]);
            *(float4*)&hL[j][0] = hv;
        }
        __syncthreads();
    }

    // final FC + sigmoid: 4 batches x 51 feats = 204 tasks
    if (tid < 4*FEAT){
        int q = tid / FEAT, f = tid % FEAT;
        float acc = 0.f;
        #pragma unroll 8
        for (int i=0;i<HID;i++) acc += hL[i][q]*FCNT[i*FEAT+f];
        out[(size_t)(b0+q)*FEAT + f] = sigmf(acc + fcb[f]);
    }
}

extern "C" void kernel_launch(void* const* d_in, const int* in_sizes, int n_in,
                              void* d_out, int out_size, void* d_ws, size_t ws_size,
                              hipStream_t stream)
{
    const float* src = (const float*)d_in[0];
    const float* w1w = (const float*)d_in[2];
    const float* w1b = (const float*)d_in[3];
    const float* w2w = (const float*)d_in[4];
    const float* w2b = (const float*)d_in[5];
    const float* meta= (const float*)d_in[6];
    const float* Wq = (const float*)d_in[7];  const float* bq = (const float*)d_in[8];
    const float* Wk = (const float*)d_in[9];  const float* bk = (const float*)d_in[10];
    const float* Wv = (const float*)d_in[11]; const float* bv = (const float*)d_in[12];
    const float* Wo = (const float*)d_in[13]; const float* bo = (const float*)d_in[14];
    const float* l1s= (const float*)d_in[15]; const float* l1b= (const float*)d_in[16];
    const float* fw1= (const float*)d_in[17]; const float* fb1= (const float*)d_in[18];
    const float* fw2= (const float*)d_in[19]; const float* fb2= (const float*)d_in[20];
    const float* l2s= (const float*)d_in[21]; const float* l2b= (const float*)d_in[22];
    const float* wih= (const float*)d_in[23]; const float* whh= (const float*)d_in[24];
    const float* bih= (const float*)d_in[25]; const float* bhh= (const float*)d_in[26];
    const float* h0 = (const float*)d_in[27];
    const float* fcw= (const float*)d_in[28]; const float* fcb= (const float*)d_in[29];

    float* ws = (float*)d_ws;
    float* X    = ws;                  // 705024
    float* Q    = X    + 705024;
    float* K    = Q    + 705024;
    float* V    = K    + 705024;
    float* GI   = V    + 705024;       // 1880064
    float* WIHT = GI   + 1880064;      // 280908
    float* WHHT = WIHT + 280908;       // 280908 + 64 pad (idle-lane overshoot)
    float* FCNT = WHHT + 280972;       // 15606
    float* ODf  = FCNT + 15606;        // 491520
    int*   TASKS= (int*)(ODf + 491520);    // 81920
    int*   RMAP = TASKS + 81920;           // 117504
    int*   NT   = RMAP + 117504;           // 256
    float2* OD  = (float2*)ODf;
    float* outp = (float*)d_out;

    embed_tasks<<<256, 512, 0, stream>>>(src, w1w, w1b, w2w, w2b, meta,
                                         Wq,bq,Wk,bk,Wv,bv, wih, whh, fcw,
                                         WIHT, WHHT, FCNT,
                                         X,Q,K,V, TASKS, RMAP, NT);
    {
        dim3 g(768, 4);
        attn_topk<<<g, 256, 0, stream>>>(Q, K, V, TASKS, NT, OD);
    }
    {
        dim3 g(4, 256);
        post_gi<<<g, 256, 0, stream>>>(X, OD, RMAP, Wo, bo, l1s, l1b,
                                       fw1, fb1, fw2, fb2, l2s, l2b,
                                       WIHT, bih, GI);
    }
    gru_fcn<<<64, 320, 0, stream>>>(GI, WHHT, bhh, h0, FCNT, fcb, outp);
}

// Round 9
// 246.651 us; speedup vs baseline: 3.4344x; 1.5115x over previous
//
#include <hip/hip_runtime.h>
#include <math.h>

#define WWIN 9
#define BATCH 256
#define FEAT 51
#define TT 459          // WWIN*FEAT
#define EMBD 6
#define HID 306
#define G3 918
#define FFND 12
#define TOPM 80
#define MAXTASK 320
#define NPAIR 153       // HID/2
#define WSTRIDE 920     // padded col stride of packed weights

__device__ __forceinline__ float leakyf(float v){ return v >= 0.f ? v : 0.01f*v; }
__device__ __forceinline__ float sigmf(float v){ return 1.f/(1.f+__expf(-v)); }

__device__ __forceinline__ unsigned fkey(float s){
    unsigned fb = __float_as_uint(s);
    unsigned m = (unsigned)((int)fb >> 31);
    return fb ^ (m | 0x80000000u);
}
__device__ __forceinline__ float fkey_inv(unsigned k){
    unsigned fb = (k & 0x80000000u) ? (k ^ 0x80000000u) : ~k;
    return __uint_as_float(fb);
}
// round-to-nearest-even f32 -> bf16 (returns low 16 bits)
__device__ __forceinline__ unsigned bfrne(float f){
    unsigned u = __float_as_uint(f);
    u += 0x7fffu + ((u >> 16) & 1u);
    return u >> 16;
}

// ---- DPP wave64 reductions ----
template<int CTRL, int RMASK>
__device__ __forceinline__ float dpp_add(float v){
    int r = __builtin_amdgcn_update_dpp(0, __float_as_int(v), CTRL, RMASK, 0xf, true);
    return v + __int_as_float(r);
}
__device__ __forceinline__ float wave_fsum(float v){
    v = dpp_add<0x111, 0xf>(v);
    v = dpp_add<0x112, 0xf>(v);
    v = dpp_add<0x114, 0xf>(v);
    v = dpp_add<0x118, 0xf>(v);
    v = dpp_add<0x142, 0xa>(v);
    v = dpp_add<0x143, 0xc>(v);
    return __int_as_float(__builtin_amdgcn_readlane(__float_as_int(v), 63));
}
template<int CTRL, int RMASK>
__device__ __forceinline__ unsigned dpp_min(unsigned v){
    unsigned r = (unsigned)__builtin_amdgcn_update_dpp((int)v, (int)v, CTRL, RMASK, 0xf, false);
    return v < r ? v : r;
}
__device__ __forceinline__ unsigned wave_umin(unsigned v){
    v = dpp_min<0x111, 0xf>(v);
    v = dpp_min<0x112, 0xf>(v);
    v = dpp_min<0x114, 0xf>(v);
    v = dpp_min<0x118, 0xf>(v);
    v = dpp_min<0x142, 0xa>(v);
    v = dpp_min<0x143, 0xc>(v);
    return (unsigned)__builtin_amdgcn_readlane((int)v, 63);
}

// ================= L1: embedding + QKV + task build + weight transforms =================
__global__ __launch_bounds__(512) void embed_tasks(
    const float* __restrict__ src,
    const float* __restrict__ w1w, const float* __restrict__ w1b,
    const float* __restrict__ w2w, const float* __restrict__ w2b,
    const float* __restrict__ meta,
    const float* __restrict__ Wq, const float* __restrict__ bq,
    const float* __restrict__ Wk, const float* __restrict__ bk,
    const float* __restrict__ Wv, const float* __restrict__ bv,
    const float* __restrict__ wih, const float* __restrict__ whh,
    const float* __restrict__ fcw,
    float* __restrict__ WIHT, unsigned* __restrict__ WHB, float* __restrict__ FCNT,
    float* __restrict__ X, float* __restrict__ Q,
    float* __restrict__ K, float* __restrict__ V,
    int* __restrict__ TASKS, int* __restrict__ ROWMAP, int* __restrict__ NT)
{
    __shared__ int sbuck[TT];
    int b = blockIdx.x;
    int t = threadIdx.x;

    // WIH transpose (f32, for post_gi)
    for (int idx = blockIdx.x*512 + threadIdx.x; idx < G3*HID; idx += 256*512){
        int o = idx / HID, i = idx % HID;
        WIHT[i*G3 + o] = wih[idx];
    }
    // WHH -> packed bf16 pairs: WHB[p*WSTRIDE + c] = bf16(whh[c][2p]) | bf16(whh[c][2p+1])<<16
    for (int idx = blockIdx.x*512 + threadIdx.x; idx < NPAIR*WSTRIDE; idx += 256*512){
        int p = idx / WSTRIDE, c = idx % WSTRIDE;
        unsigned v = 0u;
        if (c < G3){
            unsigned lo = bfrne(whh[(size_t)c*HID + 2*p]);
            unsigned hi = bfrne(whh[(size_t)c*HID + 2*p + 1]);
            v = lo | (hi << 16);
        }
        WHB[idx] = v;
    }
    for (int idx = blockIdx.x*512 + threadIdx.x; idx < FEAT*HID; idx += 256*512){
        int f = idx / HID, i = idx % HID;
        FCNT[i*FEAT + f] = fcw[idx];
    }

    if (t < TT){
        int w = t / FEAT, f = t % FEAT;
        float s = src[(w*BATCH + b)*FEAT + f];
        float h1[EMBD], h2[EMBD];
        #pragma unroll
        for (int i=0;i<EMBD;i++) h1[i] = leakyf(s*w1w[f*EMBD+i] + w1b[f*EMBD+i]);
        #pragma unroll
        for (int j=0;j<EMBD;j++){
            float a = 0.f;
            #pragma unroll
            for (int i=0;i<EMBD;i++) a += h1[i]*w2w[(f*EMBD+j)*EMBD+i];
            h2[j] = a + w2b[f*EMBD+j];
        }
        float z[EMBD];
        float m = -INFINITY; int jm = 0;
        #pragma unroll
        for (int j=0;j<EMBD;j++){
            z[j] = (h2[j] + 0.5f*h1[j]) * 1e+05f;
            if (z[j] > m){ m = z[j]; jm = j; }
        }
        float se = 0.f;
        #pragma unroll
        for (int j=0;j<EMBD;j++){ z[j] = expf(z[j]-m); se += z[j]; }
        float inv = 1.0f / se;
        #pragma unroll
        for (int j=0;j<EMBD;j++) z[j] *= inv;
        sbuck[t] = jm;

        float xr[EMBD];
        #pragma unroll
        for (int e=0;e<EMBD;e++){
            float a = 0.f;
            #pragma unroll
            for (int i=0;i<EMBD;i++) a += z[i]*meta[(f*EMBD+i)*EMBD+e];
            xr[e] = a * 2.449489742783178f;
        }
        float* xp = X + (b*TT + t)*EMBD;
        float* qp = Q + (b*TT + t)*EMBD;
        float* kp = K + (b*TT + t)*EMBD;
        float* vp = V + (b*TT + t)*EMBD;
        #pragma unroll
        for (int e=0;e<EMBD;e++){
            xp[e] = xr[e];
            float aq=0.f, ak=0.f, av=0.f;
            #pragma unroll
            for (int i=0;i<EMBD;i++){
                aq += xr[i]*Wq[e*EMBD+i];
                ak += xr[i]*Wk[e*EMBD+i];
                av += xr[i]*Wv[e*EMBD+i];
            }
            qp[e] = aq + bq[e];
            kp[e] = ak + bk[e];
            vp[e] = av + bv[e];
        }
    }
    __syncthreads();
    if (threadIdx.x < 64){
        int f = threadIdx.x;
        unsigned mask = 0; int repw[6]; int cnt = 0;
        if (f < FEAT){
            #pragma unroll
            for (int w=0; w<WWIN; w++){
                int j = sbuck[w*FEAT + f];
                if (!((mask>>j) & 1u)){ mask |= 1u<<j; repw[j] = w; }
            }
            cnt = __popc(mask);
        }
        int inc = cnt;
        #pragma unroll
        for (int off=1; off<64; off<<=1){
            int n = __shfl_up(inc, off, 64);
            if (threadIdx.x >= off) inc += n;
        }
        int offset = inc - cnt;
        if (f < FEAT){
            int rk = 0;
            #pragma unroll
            for (int j=0;j<6;j++){
                if ((mask>>j) & 1u){
                    TASKS[b*MAXTASK + offset + rk] = (f<<8) | (j<<4) | repw[j];
                    rk++;
                }
            }
            #pragma unroll
            for (int w=0;w<WWIN;w++){
                int j = sbuck[w*FEAT + f];
                int r = __popc(mask & ((1u<<j)-1u));
                ROWMAP[b*TT + w*FEAT + f] = offset + r;
            }
        }
        if (threadIdx.x == 63) NT[b] = inc;
    }
}

// ================= L2: attention (distinct rows, count-ge descent, DPP reduce) =================
__global__ __launch_bounds__(256) void attn_topk(
    const float* __restrict__ Q, const float* __restrict__ K,
    const float* __restrict__ V, const int* __restrict__ TASKS,
    const int* __restrict__ NT, float2* __restrict__ OD)
{
    __shared__ float2 kk[512], vv[512];
    int blk = blockIdx.x;
    int b = blk / 3, h = blk % 3;
    const int base = b*TT*EMBD + 2*h;
    for (int t = threadIdx.x; t < 512; t += 256){
        if (t < TT){
            kk[t] = make_float2(K[base + t*EMBD], K[base + t*EMBD + 1]);
            vv[t] = make_float2(V[base + t*EMBD], V[base + t*EMBD + 1]);
        } else {
            kk[t] = make_float2(0.f, 0.f);
            vv[t] = make_float2(0.f, 0.f);
        }
    }
    __syncthreads();
    int nt = NT[b];
    int wave = threadIdx.x >> 6, lane = threadIdx.x & 63;
    const float SC = 0.7071067811865476f;
    for (int idx = blockIdx.y*4 + wave; idx < nt; idx += 16){
        int pk = TASKS[b*MAXTASK + idx];
        int rep_t = (pk & 15)*FEAT + (pk >> 8);
        float q0 = Q[base + rep_t*EMBD]     * SC;
        float q1 = Q[base + rep_t*EMBD + 1] * SC;

        float sv[8]; unsigned uk[8];
        #pragma unroll
        for (int i=0;i<8;i++){
            int j = lane + (i<<6);
            float2 kv = kk[j];
            float s = q0*kv.x + q1*kv.y;
            sv[i] = s;
            uk[i] = (j < TT) ? fkey(s) : 0u;
        }
        unsigned T = 0; int exact = 0;
        for (int bit = 31; bit >= 0; --bit){
            unsigned Tp = T | (1u<<bit);
            int c = 0;
            #pragma unroll
            for (int i=0;i<8;i++) c += __popcll(__ballot(uk[i] >= Tp));
            if (c >= TOPM) T = Tp;
            if (c == TOPM){ exact = 1; break; }
        }
        unsigned kth;
        if (exact){
            unsigned mn = 0xFFFFFFFFu;
            #pragma unroll
            for (int i=0;i<8;i++) mn = min(mn, (uk[i] >= T) ? uk[i] : 0xFFFFFFFFu);
            kth = wave_umin(mn);
        } else {
            kth = T;
        }
        float skth = fkey_inv(kth);
        float den=0.f, ox=0.f, oy=0.f;
        #pragma unroll
        for (int i=0;i<8;i++){
            float2 v2 = vv[lane + (i<<6)];
            float p = __expf(sv[i] - skth);
            p = (uk[i] >= kth) ? p : 0.f;
            den += p; ox += p*v2.x; oy += p*v2.y;
        }
        den = wave_fsum(den);
        ox  = wave_fsum(ox);
        oy  = wave_fsum(oy);
        if (lane == 0){
            float id = 1.0f/den;
            OD[(b*3 + h)*MAXTASK + idx] = make_float2(ox*id, oy*id);
        }
    }
}

// ================= L3: post-block fused into GI matmul (SEQ lives in LDS only) =================
__global__ __launch_bounds__(256) void post_gi(
    const float* __restrict__ X, const float2* __restrict__ OD,
    const int* __restrict__ ROWMAP,
    const float* __restrict__ Wo, const float* __restrict__ bo,
    const float* __restrict__ l1s, const float* __restrict__ l1b,
    const float* __restrict__ fw1, const float* __restrict__ fb1,
    const float* __restrict__ fw2, const float* __restrict__ fb2,
    const float* __restrict__ l2s, const float* __restrict__ l2b,
    const float* __restrict__ WIHT, const float* __restrict__ bih,
    float* __restrict__ GI)
{
    __shared__ float sL[8][HID];
    int gy = blockIdx.y, gx = blockIdx.x;
    for (int idx = threadIdx.x; idx < 8*FEAT; idx += 256){
        int k = idx / FEAT, ff = idx % FEAT;
        int r = gy*8 + k;
        int w = r >> 8, b = r & 255;
        int t = w*FEAT + ff;
        const float* xr = X + (b*TT + t)*EMBD;
        int rm = ROWMAP[b*TT + t];
        float orow[EMBD];
        #pragma unroll
        for (int h=0;h<3;h++){
            float2 od = OD[(b*3 + h)*MAXTASK + rm];
            orow[2*h]   = od.x;
            orow[2*h+1] = od.y;
        }
        float y[EMBD];
        #pragma unroll
        for (int e=0;e<EMBD;e++){
            float a = 0.f;
            #pragma unroll
            for (int e2=0;e2<EMBD;e2++) a += orow[e2]*Wo[e*EMBD+e2];
            y[e] = xr[e] + a + bo[e];
        }
        float mu=0.f;
        #pragma unroll
        for (int e=0;e<EMBD;e++) mu += y[e];
        mu *= (1.f/6.f);
        float var=0.f;
        #pragma unroll
        for (int e=0;e<EMBD;e++){ float d = y[e]-mu; var += d*d; }
        var *= (1.f/6.f);
        float isd = 1.0f / sqrtf(var + 1e-05f);
        float xn[EMBD];
        #pragma unroll
        for (int e=0;e<EMBD;e++) xn[e] = (y[e]-mu)*isd*l1s[e] + l1b[e];
        float hd[FFND];
        #pragma unroll
        for (int kk2=0;kk2<FFND;kk2++){
            float a = fb1[kk2];
            #pragma unroll
            for (int e=0;e<EMBD;e++) a += xn[e]*fw1[kk2*EMBD+e];
            hd[kk2] = fmaxf(a, 0.f);
        }
        float y2[EMBD];
        #pragma unroll
        for (int e=0;e<EMBD;e++){
            float a = fb2[e];
            #pragma unroll
            for (int kk2=0;kk2<FFND;kk2++) a += hd[kk2]*fw2[e*FFND+kk2];
            y2[e] = xn[e] + a;
        }
        float mu2=0.f;
        #pragma unroll
        for (int e=0;e<EMBD;e++) mu2 += y2[e];
        mu2 *= (1.f/6.f);
        float var2=0.f;
        #pragma unroll
        for (int e=0;e<EMBD;e++){ float d = y2[e]-mu2; var2 += d*d; }
        var2 *= (1.f/6.f);
        float isd2 = 1.0f / sqrtf(var2 + 1e-05f);
        #pragma unroll
        for (int e=0;e<EMBD;e++) sL[k][ff*EMBD+e] = (y2[e]-mu2)*isd2*l2s[e] + l2b[e];
    }
    __syncthreads();
    int col = gx*256 + threadIdx.x;
    if (col >= G3) return;
    float acc[8];
    #pragma unroll
    for (int k=0;k<8;k++) acc[k] = 0.f;
    for (int i=0;i<HID;i++){
        float wv = WIHT[i*G3 + col];
        #pragma unroll
        for (int k=0;k<8;k++) acc[k] += sL[k][i]*wv;
    }
    float bb = bih[col];
    #pragma unroll
    for (int k=0;k<8;k++) GI[(size_t)(gy*8+k)*G3 + col] = acc[k] + bb;
}

// ================= L4: GRU 8 steps + FC; 256 blocks x 1 batch; bf16-packed weights =================
// thread j owns cols (j, 306+j, 612+j). Weight pairs (i=2p,2p+1) packed in one dword.
#define PFP 9   // pairs per chunk; 153 = 17*9

#define LOADP(buf, c_) { \
    int p0_ = (c_)*PFP; \
    _Pragma("unroll") \
    for (int r=0;r<PFP;r++){ \
        const unsigned* wp = WHB + (size_t)(p0_+r)*WSTRIDE + jc; \
        buf[3*r] = wp[0]; buf[3*r+1] = wp[HID]; buf[3*r+2] = wp[2*HID]; \
    } }

#define COMPP(buf, c_) { \
    int p0_ = (c_)*PFP; \
    _Pragma("unroll") \
    for (int r=0;r<PFP;r++){ \
        float2 h2 = *(const float2*)&hL[2*(p0_+r)]; \
        unsigned pr_ = buf[3*r], pz_ = buf[3*r+1], pn_ = buf[3*r+2]; \
        float wr0 = __uint_as_float(pr_ << 16), wr1 = __uint_as_float(pr_ & 0xffff0000u); \
        float wz0 = __uint_as_float(pz_ << 16), wz1 = __uint_as_float(pz_ & 0xffff0000u); \
        float wn0 = __uint_as_float(pn_ << 16), wn1 = __uint_as_float(pn_ & 0xffff0000u); \
        ar = fmaf(wr0, h2.x, fmaf(wr1, h2.y, ar)); \
        az = fmaf(wz0, h2.x, fmaf(wz1, h2.y, az)); \
        an = fmaf(wn0, h2.x, fmaf(wn1, h2.y, an)); \
    } }

__global__ __launch_bounds__(320) void gru_fcn(
    const float* __restrict__ GI, const unsigned* __restrict__ WHB,
    const float* __restrict__ bhh, const float* __restrict__ h0,
    const float* __restrict__ FCNT, const float* __restrict__ fcb,
    float* __restrict__ out)
{
    __shared__ float hL[HID + 2];
    int b = blockIdx.x;
    int tid = threadIdx.x;
    if (tid < HID) hL[tid] = h0[(size_t)b*HID + tid];
    if (tid >= HID && tid < HID+2) hL[tid] = 0.f;
    __syncthreads();

    int j = tid;
    bool act = (j < HID);
    int jc = act ? j : 0;
    float br = bhh[jc], bz = bhh[HID+jc], bn = bhh[2*HID+jc];

    for (int step = 0; step < 8; ++step){
        const float* gi = GI + ((size_t)step*BATCH + b)*G3;
        float gr = gi[jc], gz = gi[HID+jc], gn = gi[2*HID+jc];
        float ar = 0.f, az = 0.f, an = 0.f;
        unsigned bufA[3*PFP], bufB[3*PFP];
        LOADP(bufA, 0);
        #pragma unroll 1
        for (int p = 0; p < 8; ++p){
            LOADP(bufB, 2*p+1);
            COMPP(bufA, 2*p);
            LOADP(bufA, 2*p+2);
            COMPP(bufB, 2*p+1);
        }
        COMPP(bufA, 16);
        float hold = hL[jc];
        __syncthreads();   // all reads of hL done
        if (act){
            float rr = sigmf(gr + ar + br);
            float zz = sigmf(gz + az + bz);
            float nn = tanhf(gn + rr*(an + bn));
            hL[j] = (1.f - zz)*nn + zz*hold;
        }
        __syncthreads();
    }

    // final FC + sigmoid: 51 outputs for this batch
    if (tid < FEAT){
        int f = tid;
        float acc = 0.f;
        #pragma unroll 6
        for (int i=0;i<HID;i++) acc += hL[i]*FCNT[i*FEAT+f];
        out[(size_t)b*FEAT + f] = sigmf(acc + fcb[f]);
    }
}

extern "C" void kernel_launch(void* const* d_in, const int* in_sizes, int n_in,
                              void* d_out, int out_size, void* d_ws, size_t ws_size,
                              hipStream_t stream)
{
    const float* src = (const float*)d_in[0];
    const float* w1w = (const float*)d_in[2];
    const float* w1b = (const float*)d_in[3];
    const float* w2w = (const float*)d_in[4];
    const float* w2b = (const float*)d_in[5];
    const float* meta= (const float*)d_in[6];
    const float* Wq = (const float*)d_in[7];  const float* bq = (const float*)d_in[8];
    const float* Wk = (const float*)d_in[9];  const float* bk = (const float*)d_in[10];
    const float* Wv = (const float*)d_in[11]; const float* bv = (const float*)d_in[12];
    const float* Wo = (const float*)d_in[13]; const float* bo = (const float*)d_in[14];
    const float* l1s= (const float*)d_in[15]; const float* l1b= (const float*)d_in[16];
    const float* fw1= (const float*)d_in[17]; const float* fb1= (const float*)d_in[18];
    const float* fw2= (const float*)d_in[19]; const float* fb2= (const float*)d_in[20];
    const float* l2s= (const float*)d_in[21]; const float* l2b= (const float*)d_in[22];
    const float* wih= (const float*)d_in[23]; const float* whh= (const float*)d_in[24];
    const float* bih= (const float*)d_in[25]; const float* bhh= (const float*)d_in[26];
    const float* h0 = (const float*)d_in[27];
    const float* fcw= (const float*)d_in[28]; const float* fcb= (const float*)d_in[29];

    float* ws = (float*)d_ws;
    float* X    = ws;                  // 705024
    float* Q    = X    + 705024;
    float* K    = Q    + 705024;
    float* V    = K    + 705024;
    float* GI   = V    + 705024;       // 1880064
    float* WIHT = GI   + 1880064;      // 280908
    unsigned* WHB = (unsigned*)(WIHT + 280908);   // 153*920 = 140760
    float* FCNT = (float*)(WHB + 140760);          // 15606
    float* ODf  = FCNT + 15606;        // 491520
    int*   TASKS= (int*)(ODf + 491520);    // 81920
    int*   RMAP = TASKS + 81920;           // 117504
    int*   NT   = RMAP + 117504;           // 256
    float2* OD  = (float2*)ODf;
    float* outp = (float*)d_out;

    embed_tasks<<<256, 512, 0, stream>>>(src, w1w, w1b, w2w, w2b, meta,
                                         Wq,bq,Wk,bk,Wv,bv, wih, whh, fcw,
                                         WIHT, WHB, FCNT,
                                         X,Q,K,V, TASKS, RMAP, NT);
    {
        dim3 g(768, 4);
        attn_topk<<<g, 256, 0, stream>>>(Q, K, V, TASKS, NT, OD);
    }
    {
        dim3 g(4, 256);
        post_gi<<<g, 256, 0, stream>>>(X, OD, RMAP, Wo, bo, l1s, l1b,
                                       fw1, fb1, fw2, fb2, l2s, l2b,
                                       WIHT, bih, GI);
    }
    gru_fcn<<<256, 320, 0, stream>>>(GI, WHB, bhh, h0, FCNT, fcb, outp);
}